// Round 4
// baseline (170.670 us; speedup 1.0000x reference)
//
#include <hip/hip_runtime.h>
#include <hip/hip_fp16.h>

typedef _Float16 half8 __attribute__((ext_vector_type(8)));
typedef __attribute__((ext_vector_type(4))) float f32x4;

#define OUT_ELEMS 8388608
#define N_VEC 32768

// ws layout (bytes):
// 0      counts int[1024]   (zeroed by prep block 0)
// 4096   loss   float       (zeroed by prep)
// 4100   ticket int         (zeroed by prep)
// 8192   sq     float[1024]
// 16384  chs    ushort[1024*256]  (fp16 of 1024*cb, scale exact pow2)

// ---- prep: zero accumulators + codebook -> fp16*1024 + ||c||^2 ----
__global__ __launch_bounds__(256) void prep_kernel(const float* __restrict__ cb,
        unsigned short* __restrict__ chs, float* __restrict__ sq,
        int* __restrict__ counts, float* __restrict__ loss, int* __restrict__ ticket) {
    const int t = threadIdx.x;
    if (blockIdx.x == 0) {
        ((int4*)counts)[t] = make_int4(0, 0, 0, 0);
        if (t == 0) { *loss = 0.f; *ticket = 0; }
    }
    const int row = blockIdx.x * 16 + (t >> 4);
    const int d0 = (t & 15) * 16;
    const float* src = cb + row * 256 + d0;
    half8 h0, h1;
    float s = 0.f;
#pragma unroll
    for (int i = 0; i < 16; ++i) {
        const float v = src[i];
        s += v * v;
        const _Float16 h = (_Float16)(v * 1024.f);
        if (i < 8) h0[i] = h; else h1[i - 8] = h;
    }
    *(half8*)(chs + row * 256 + d0) = h0;
    *(half8*)(chs + row * 256 + d0 + 8) = h1;
#pragma unroll
    for (int off = 1; off < 16; off <<= 1) s += __shfl_xor(s, off);
    if ((t & 15) == 0) sq[row] = s;
}

// ---- fused: argmin (fp16 MFMA, all 1024 codes) + hist + loss + scatter + finalize ----
// grid 256 (1 block/CU), 512 thr = 8 waves x 16 rows = 128 rows/block.
__global__ __launch_bounds__(512, 1) void fused_kernel(
    const float* __restrict__ x, const unsigned short* __restrict__ chs,
    const float* __restrict__ sq, const float* __restrict__ cb,
    float* __restrict__ out, int* __restrict__ counts,
    float* __restrict__ loss_accum, int* __restrict__ ticket)
{
    __shared__ union {
        unsigned short Bs[2][32][264];   // fp16 B tiles, dbuf (33792 B)
        float Q[32][257];                // scatter staging (32896 B)
    } U;
    __shared__ float Ssq[1024];
    __shared__ float xsqL[128];
    __shared__ int   codeL[128];
    __shared__ float wsum[8];
    __shared__ int   lastflag;

    const int t = threadIdx.x;
    const int lane = t & 63;
    const int w = t >> 6;            // wave 0..7
    const int m = lane & 15;         // A-row / B-col class
    const int q = lane >> 4;         // quad
    const int bid = blockIdx.x;
    const int batch = bid >> 3;
    const int hwb = (bid & 7) << 7;  // 128 rows within one batch

    Ssq[t] = sq[t];
    Ssq[t + 512] = sq[t + 512];

    // stage 0 of B: 32 codes x 256 d fp16 = 16 KB
    const int scode = t >> 4;        // 0..31
    const int sk = t & 15;           // 16-half chunk
    {
        const unsigned short* g = chs + scode * 256 + sk * 16;
        *(half8*)&U.Bs[0][scode][sk * 16]     = *(const half8*)(g);
        *(half8*)&U.Bs[0][scode][sk * 16 + 8] = *(const half8*)(g + 8);
    }

    // A prologue: 16 rows/wave, full D=256 in fp16 frags; fused ||x||^2
    const float* xb = x + (size_t)batch * (256 * 1024) + hwb + w * 16 + m;
    half8 Ah[8];
    float xs = 0.f;
#pragma unroll
    for (int ks = 0; ks < 8; ++ks) {
        half8 a;
#pragma unroll
        for (int j = 0; j < 8; ++j) {
            const float v = xb[(size_t)((ks * 32 + q * 8 + j) << 10)];
            xs += v * v;
            a[j] = (_Float16)v;
        }
        Ah[ks] = a;
    }
    xs += __shfl_xor(xs, 16);
    xs += __shfl_xor(xs, 32);
    if (q == 0) xsqL[w * 16 + m] = xs;

    float bestv[4];
    int   bestk[4];
#pragma unroll
    for (int r = 0; r < 4; ++r) { bestv[r] = 3.4e38f; bestk[r] = 0; }

    // K-loop: 32 stages of 32 codes; 1 barrier/stage, prefetch before barrier
    for (int s = 0; s < 32; ++s) {
        const int buf = s & 1;
        half8 n0, n1;
        if (s + 1 < 32) {
            const unsigned short* g = chs + ((s + 1) * 32 + scode) * 256 + sk * 16;
            n0 = *(const half8*)(g);
            n1 = *(const half8*)(g + 8);
        }
        __syncthreads();
        f32x4 a0 = {0.f, 0.f, 0.f, 0.f}, a1 = {0.f, 0.f, 0.f, 0.f};
#pragma unroll
        for (int ks = 0; ks < 8; ++ks) {
            const half8 b0 = *(const half8*)&U.Bs[buf][m][ks * 32 + q * 8];
            const half8 b1 = *(const half8*)&U.Bs[buf][16 + m][ks * 32 + q * 8];
            a0 = __builtin_amdgcn_mfma_f32_16x16x32_f16(Ah[ks], b0, a0, 0, 0, 0);
            a1 = __builtin_amdgcn_mfma_f32_16x16x32_f16(Ah[ks], b1, a1, 0, 0, 0);
        }
        const int   c0 = s * 32 + m,  c1 = c0 + 16;
        const float s0 = Ssq[c0],     s1 = Ssq[c1];
#pragma unroll
        for (int r = 0; r < 4; ++r) {
            const float d0 = fmaf(-0.001953125f, a0[r], s0);  // -2/1024: undo B scale
            if (d0 < bestv[r]) { bestv[r] = d0; bestk[r] = c0; }
            const float d1 = fmaf(-0.001953125f, a1[r], s1);
            if (d1 < bestv[r]) { bestv[r] = d1; bestk[r] = c1; }
        }
        if (s + 1 < 32) {   // own reads of buf done; buf^1 readers all passed top barrier
            *(half8*)&U.Bs[buf ^ 1][scode][sk * 16]     = n0;
            *(half8*)&U.Bs[buf ^ 1][scode][sk * 16 + 8] = n1;
        }
    }

    // per-row final argmin (reduce over 16 code-classes); tie -> lower k
    float rsum = 0.f;
#pragma unroll
    for (int r = 0; r < 4; ++r) {
        float v = bestv[r];
        int   k = bestk[r];
#pragma unroll
        for (int d = 1; d < 16; d <<= 1) {
            const float ov = __shfl_xor(v, d);
            const int   ok = __shfl_xor(k, d);
            if (ov < v || (ov == v && ok < k)) { v = ov; k = ok; }
        }
        if (m == 0) {
            const int row = w * 16 + q * 4 + r;
            codeL[row] = k;
            atomicAdd(&counts[k], 1);
            rsum += xsqL[row] + v;          // ||x - c||^2
        }
    }
#pragma unroll
    for (int off = 32; off > 0; off >>= 1) rsum += __shfl_down(rsum, off);
    if (lane == 0) wsum[w] = rsum;
    __syncthreads();                        // also: all B-LDS reads done before Q reuse
    if (t == 0) {
        float bs = 0.f;
#pragma unroll
        for (int i = 0; i < 8; ++i) bs += wsum[i];
        atomicAdd(loss_accum, bs);
        __threadfence();
        lastflag = (atomicAdd(ticket, 1) == 255);
    }

    // scatter: 4 passes of 32 rows; stage selected cb rows in LDS, write coalesced
    for (int p = 0; p < 4; ++p) {
        __syncthreads();                    // Q region free; codeL/lastflag visible
        const int r = t >> 4;               // 0..31
        const int sk2 = t & 15;
        const float* src = cb + (size_t)codeL[p * 32 + r] * 256 + sk2 * 16;
        const float4 v0 = *(const float4*)(src);
        const float4 v1 = *(const float4*)(src + 4);
        const float4 v2 = *(const float4*)(src + 8);
        const float4 v3 = *(const float4*)(src + 12);
        float* qd = &U.Q[r][sk2 * 16];
        qd[0]=v0.x; qd[1]=v0.y; qd[2]=v0.z; qd[3]=v0.w;
        qd[4]=v1.x; qd[5]=v1.y; qd[6]=v1.z; qd[7]=v1.w;
        qd[8]=v2.x; qd[9]=v2.y; qd[10]=v2.z; qd[11]=v2.w;
        qd[12]=v3.x; qd[13]=v3.y; qd[14]=v3.z; qd[15]=v3.w;
        __syncthreads();
        float* dst = out + (size_t)batch * (256 * 1024) + hwb + p * 32;
#pragma unroll 4
        for (int i = 0; i < 16; ++i) {
            const int flat = i * 512 + t;
            const int c = flat >> 5;
            const int hwl = flat & 31;
            dst[(size_t)c * 1024 + hwl] = U.Q[hwl][c];
        }
    }

    // last block: finalize loss + perplexity
    if (lastflag) {
        __threadfence();
        float s2 = 0.f;
#pragma unroll
        for (int mm = 0; mm < 2; ++mm) {
            const int cnt = atomicAdd(&counts[t + 512 * mm], 0);
            const float pp = (float)cnt * (1.f / 32768.f);
            s2 += pp * logf(pp + 1e-10f);
        }
#pragma unroll
        for (int off = 32; off > 0; off >>= 1) s2 += __shfl_down(s2, off);
        if (lane == 0) wsum[w] = s2;
        __syncthreads();
        if (t == 0) {
            float total = 0.f;
#pragma unroll
            for (int i = 0; i < 8; ++i) total += wsum[i];
            out[OUT_ELEMS]     = atomicAdd(loss_accum, 0.f) * (1.25f / 8388608.f);
            out[OUT_ELEMS + 1] = expf(-total);
        }
    }
}

extern "C" void kernel_launch(void* const* d_in, const int* in_sizes, int n_in,
                              void* d_out, int out_size, void* d_ws, size_t ws_size,
                              hipStream_t stream) {
    const float* x  = (const float*)d_in[0];
    const float* cb = (const float*)d_in[1];
    float* out = (float*)d_out;
    char* wsb = (char*)d_ws;
    int*            counts = (int*)(wsb + 0);
    float*          loss   = (float*)(wsb + 4096);
    int*            ticket = (int*)(wsb + 4100);
    float*          sq     = (float*)(wsb + 8192);
    unsigned short* chs    = (unsigned short*)(wsb + 16384);

    prep_kernel<<<64, 256, 0, stream>>>(cb, chs, sq, counts, loss, ticket);
    fused_kernel<<<256, 512, 0, stream>>>(x, chs, sq, cb, out, counts, loss, ticket);
}

// Round 5
// 119.956 us; speedup vs baseline: 1.4228x; 1.4228x over previous
//
#include <hip/hip_runtime.h>
#include <hip/hip_fp16.h>

typedef _Float16 half8 __attribute__((ext_vector_type(8)));
typedef __attribute__((ext_vector_type(4))) float f32x4;

#define OUT_ELEMS 8388608

// ws layout (bytes):
// 0      counts int[1024]        (zeroed by prep block 0)
// 4096   loss   float            (zeroed by prep)
// 8192   sq     float[1024]
// 16384  chs    ushort[1024*256] (fp16 of 1024*cb; *1024 is exact pow2 scaling)
// 540672 codeG  int[32768]

// ---- prep: zero accumulators + codebook -> fp16*1024 + ||c||^2 ----
__global__ __launch_bounds__(256) void prep_kernel(const float* __restrict__ cb,
        unsigned short* __restrict__ chs, float* __restrict__ sq,
        int* __restrict__ counts, float* __restrict__ loss) {
    const int t = threadIdx.x;
    if (blockIdx.x == 0) {
        ((int4*)counts)[t] = make_int4(0, 0, 0, 0);
        if (t == 0) *loss = 0.f;
    }
    const int row = blockIdx.x * 16 + (t >> 4);
    const int d0 = (t & 15) * 16;
    const float* src = cb + row * 256 + d0;
    half8 h0, h1;
    float s = 0.f;
#pragma unroll
    for (int i = 0; i < 16; ++i) {
        const float v = src[i];
        s += v * v;
        const _Float16 h = (_Float16)(v * 1024.f);
        if (i < 8) h0[i] = h; else h1[i - 8] = h;
    }
    *(half8*)(chs + row * 256 + d0) = h0;
    *(half8*)(chs + row * 256 + d0 + 8) = h1;
#pragma unroll
    for (int off = 1; off < 16; off <<= 1) s += __shfl_xor(s, off);
    if ((t & 15) == 0) sq[row] = s;
}

// ---- argmin: grid 256 (1/CU), 512 thr = 8 waves.
// waves 0-3: codes 0-511; waves 4-7: codes 512-1023; both on the same 128 rows.
// Per wave M=32 (2 A-frags) sharing each B ds_read_b128 -> MFMA:LDS = 2:1.
__global__ __launch_bounds__(512, 2) void argmin_kernel(
    const float* __restrict__ x, const unsigned short* __restrict__ chs,
    const float* __restrict__ sq, int* __restrict__ codeG,
    int* __restrict__ counts, float* __restrict__ loss_accum)
{
    __shared__ unsigned short Bs[2][2][16][264];   // [dbuf][wavegroup][code][d], 33.8 KB
    __shared__ float mv[2][128];
    __shared__ int   mk[2][128];
    __shared__ float xsqL[128];
    __shared__ float wsum[2];

    const int t = threadIdx.x;
    const int lane = t & 63;
    const int w  = t >> 6;
    const int wg = w >> 2;            // code-group 0/1
    const int wl = w & 3;             // row-subgroup 0..3
    const int m = lane & 15;
    const int q = lane >> 4;
    const int kb = wg << 9;
    const int bid = blockIdx.x;
    const int batch = bid >> 3;
    const int rowb = wl * 32;
    const int hwb = (bid & 7) << 7;
    const float* xb = x + (size_t)batch * 262144 + hwb + rowb + m;

    // B stage 0: each half of the block stages its group's 16-code tile (8 KB)
    const int g  = t >> 8;            // == wg for this thread
    const int tt = t & 255;
    const int scode = tt >> 4;
    const int sk = tt & 15;
    {
        const unsigned short* src = chs + ((g << 9) + scode) * 256 + sk * 16;
        *(half8*)&Bs[0][g][scode][sk * 16]     = *(const half8*)src;
        *(half8*)&Bs[0][g][scode][sk * 16 + 8] = *(const half8*)(src + 8);
    }

    // A prologue: 32 rows/wave, full D=256 -> fp16 frags; fused ||x||^2
    half8 Ah[2][8];
#pragma unroll
    for (int f = 0; f < 2; ++f) {
        float xs = 0.f;
#pragma unroll
        for (int ks = 0; ks < 8; ++ks) {
            half8 a;
#pragma unroll
            for (int j = 0; j < 8; ++j) {
                const float v = xb[f * 16 + ((size_t)(ks * 32 + q * 8 + j) << 10)];
                xs += v * v;
                a[j] = (_Float16)v;
            }
            Ah[f][ks] = a;
        }
        xs += __shfl_xor(xs, 16);
        xs += __shfl_xor(xs, 32);
        if (wg == 0 && q == 0) xsqL[rowb + f * 16 + m] = xs;
    }

    float bestv[2][4];
    int   bestk[2][4];
#pragma unroll
    for (int f = 0; f < 2; ++f)
#pragma unroll
        for (int r = 0; r < 4; ++r) { bestv[f][r] = 3.4e38f; bestk[f][r] = 0; }

    float sc2 = sq[kb + m];           // stage-0 ||c||^2, prefetched

    for (int s = 0; s < 32; ++s) {
        const int buf = s & 1;
        half8 n0, n1;
        float sc2n;
        if (s + 1 < 32) {             // prefetch next B tile + next sq before barrier
            const unsigned short* src = chs + ((g << 9) + (s + 1) * 16 + scode) * 256 + sk * 16;
            n0 = *(const half8*)src;
            n1 = *(const half8*)(src + 8);
            sc2n = sq[kb + (s + 1) * 16 + m];
        }
        __syncthreads();
        f32x4 a0 = {0.f, 0.f, 0.f, 0.f}, a1 = {0.f, 0.f, 0.f, 0.f};
#pragma unroll
        for (int ks = 0; ks < 8; ++ks) {
            const half8 b = *(const half8*)&Bs[buf][wg][m][ks * 32 + q * 8];
            a0 = __builtin_amdgcn_mfma_f32_16x16x32_f16(Ah[0][ks], b, a0, 0, 0, 0);
            a1 = __builtin_amdgcn_mfma_f32_16x16x32_f16(Ah[1][ks], b, a1, 0, 0, 0);
        }
        const int code = kb + s * 16 + m;
#pragma unroll
        for (int f = 0; f < 2; ++f) {
            const f32x4 a = f ? a1 : a0;
#pragma unroll
            for (int r = 0; r < 4; ++r) {
                const float d0 = fmaf(-0.001953125f, a[r], sc2);  // -2/1024 undoes B scale
                if (d0 < bestv[f][r]) { bestv[f][r] = d0; bestk[f][r] = code; }
            }
        }
        if (s + 1 < 32) {             // safe: all waves passed this stage's barrier
            *(half8*)&Bs[buf ^ 1][g][scode][sk * 16]     = n0;
            *(half8*)&Bs[buf ^ 1][g][scode][sk * 16 + 8] = n1;
            sc2 = sc2n;
        }
    }

    // per-row argmin across the 16 code-classes; tie -> lower k
#pragma unroll
    for (int f = 0; f < 2; ++f)
#pragma unroll
        for (int r = 0; r < 4; ++r) {
            float v = bestv[f][r];
            int   k = bestk[f][r];
#pragma unroll
            for (int d = 1; d < 16; d <<= 1) {
                const float ov = __shfl_xor(v, d);
                const int   ok = __shfl_xor(k, d);
                if (ov < v || (ov == v && ok < k)) { v = ov; k = ok; }
            }
            if (m == 0) {
                const int row = rowb + f * 16 + q * 4 + r;
                mv[wg][row] = v;
                mk[wg][row] = k;
            }
        }
    __syncthreads();

    // merge the two code-groups (tie -> group 0 = lower codes), hist + loss
    if (t < 128) {
        const float v0 = mv[0][t]; const int k0 = mk[0][t];
        const float v1 = mv[1][t]; const int k1 = mk[1][t];
        const int   k = (v1 < v0) ? k1 : k0;
        const float v = (v1 < v0) ? v1 : v0;
        codeG[bid * 128 + t] = k;
        atomicAdd(&counts[k], 1);
        float lp = xsqL[t] + v;       // ||x - c||^2
#pragma unroll
        for (int off = 32; off > 0; off >>= 1) lp += __shfl_down(lp, off);
        if ((t & 63) == 0) wsum[t >> 6] = lp;
    }
    __syncthreads();
    if (t == 0) atomicAdd(loss_accum, wsum[0] + wsum[1]);
}

// ---- gather: LDS transpose of 64 selected cb rows -> coalesced float4 out ----
__global__ __launch_bounds__(256) void gather_kernel(
    const float* __restrict__ cb, const int* __restrict__ codeG,
    const int* __restrict__ counts, const float* __restrict__ loss_accum,
    float* __restrict__ out)
{
    __shared__ float Q[64][257];
    __shared__ int codeL[64];
    __shared__ float wsum[4];
    const int t = threadIdx.x;
    const int bid = blockIdx.x;
    if (t < 64) codeL[t] = codeG[bid * 64 + t];
    __syncthreads();
    {   // stage: lane -> row r (2-way LDS write = free; global reads L2-hot)
        const int r = t & 63, seg = t >> 6;
        const float* src = cb + (size_t)codeL[r] * 256 + seg * 64;
#pragma unroll
        for (int i = 0; i < 16; ++i)
            *(float4*)&Q[r][seg * 64 + i * 4] = *(const float4*)(src + i * 4);
    }
    __syncthreads();
    const int batch = bid >> 4;
    const int hw0 = (bid & 15) << 6;
    const int hw4 = (t & 15) * 4;
    const int c0 = t >> 4;
    float* dst = out + (size_t)batch * 262144 + hw0 + hw4;
#pragma unroll
    for (int i = 0; i < 16; ++i) {
        const int c = c0 + i * 16;
        float4 v;
        v.x = Q[hw4 + 0][c];
        v.y = Q[hw4 + 1][c];
        v.z = Q[hw4 + 2][c];
        v.w = Q[hw4 + 3][c];
        *(float4*)(dst + (size_t)c * 1024) = v;   // 256B contiguous per 16 lanes
    }
    if (bid == 0) {   // finalize: counts/loss complete (kernel boundary ordering)
        float s = 0.f;
#pragma unroll
        for (int mm = 0; mm < 4; ++mm) {
            const float p = (float)counts[t + 256 * mm] * (1.f / 32768.f);
            s += p * logf(p + 1e-10f);
        }
#pragma unroll
        for (int off = 32; off > 0; off >>= 1) s += __shfl_down(s, off);
        if ((t & 63) == 0) wsum[t >> 6] = s;
        __syncthreads();
        if (t == 0) {
            out[OUT_ELEMS]     = loss_accum[0] * (1.25f / 8388608.f);
            out[OUT_ELEMS + 1] = expf(-(wsum[0] + wsum[1] + wsum[2] + wsum[3]));
        }
    }
}

extern "C" void kernel_launch(void* const* d_in, const int* in_sizes, int n_in,
                              void* d_out, int out_size, void* d_ws, size_t ws_size,
                              hipStream_t stream) {
    const float* x  = (const float*)d_in[0];
    const float* cb = (const float*)d_in[1];
    float* out = (float*)d_out;
    char* wsb = (char*)d_ws;
    int*            counts = (int*)(wsb + 0);
    float*          loss   = (float*)(wsb + 4096);
    float*          sq     = (float*)(wsb + 8192);
    unsigned short* chs    = (unsigned short*)(wsb + 16384);
    int*            codeG  = (int*)(wsb + 540672);

    prep_kernel<<<64, 256, 0, stream>>>(cb, chs, sq, counts, loss);
    argmin_kernel<<<256, 512, 0, stream>>>(x, chs, sq, codeG, counts, loss);
    gather_kernel<<<512, 256, 0, stream>>>(cb, codeG, counts, loss, out);
}